// Round 11
// baseline (477.121 us; speedup 1.0000x reference)
//
#include <hip/hip_runtime.h>
#include <math.h>

// PatchCore-DINOv2 anomaly score, round 11.
// Round-10 diagnosis: spill persists (WRITE 176MB) because inline f32->bf16 convert
// keeps breg[8]+convert VALU in the hot loop. Fix: one-time convert pass
// (mbl -> bf16c + exact msqg), score stages bf16 directly (16 stage VGPRs, no convert,
// no msq in-loop) -> ~203 regs < 256 cap, no spill. Refine parallelized 4x per q.

#define D 384
#define PQ 256      // q rows per score block
#define TNP 128     // bank rows per panel
#define BK 64       // k elems per chunk
#define LROW 72     // 144B LDS row stride: 2-way frag reads (free)

typedef __attribute__((ext_vector_type(8))) short short8v;
typedef __attribute__((ext_vector_type(4))) float f32x4;

static __device__ __forceinline__ unsigned short f2bf(float f) {
  unsigned u = __float_as_uint(f);
  unsigned r = 0x7FFFu + ((u >> 16) & 1u);   // RNE
  return (unsigned short)((u + r) >> 16);
}
static __device__ __forceinline__ unsigned pack2(float lo, float hi) {
  return (unsigned)f2bf(lo) | ((unsigned)f2bf(hi) << 16);
}

// ---------------- prep: normalize patches/globals ----------------
__global__ void prep_kernel(const float* __restrict__ patches,
                            const float* __restrict__ globals_x,
                            float* __restrict__ pf32,
                            unsigned short* __restrict__ pbf,
                            float* __restrict__ psq,
                            float* __restrict__ gf32,
                            float* __restrict__ gsq,
                            int Q) {
  const int row = blockIdx.x;
  const int lane = threadIdx.x;  // 64 = 1 wave
  const float* src = (row < Q) ? (patches + (size_t)row * D)
                               : (globals_x + (size_t)(row - Q) * D);
  float v[6];
  float ss = 0.f;
#pragma unroll
  for (int j = 0; j < 6; ++j) { v[j] = src[lane + 64 * j]; ss += v[j] * v[j]; }
#pragma unroll
  for (int d = 1; d < 64; d <<= 1) ss += __shfl_xor(ss, d);
  const float inv = 1.f / (sqrtf(ss) + 1e-12f);
  float pn[6]; float ps = 0.f;
#pragma unroll
  for (int j = 0; j < 6; ++j) { pn[j] = v[j] * inv; ps += pn[j] * pn[j]; }
#pragma unroll
  for (int d = 1; d < 64; d <<= 1) ps += __shfl_xor(ps, d);
  if (row < Q) {
#pragma unroll
    for (int j = 0; j < 6; ++j) {
      pf32[(size_t)row * D + lane + 64 * j] = pn[j];
      pbf[(size_t)row * D + lane + 64 * j] = f2bf(pn[j]);
    }
    if (lane == 0) psq[row] = ps;
  } else {
    const int b = row - Q;
#pragma unroll
    for (int j = 0; j < 6; ++j) gf32[(size_t)b * D + lane + 64 * j] = pn[j];
    if (lane == 0) gsq[b] = ps;
  }
}

// ---------------- convert: mbl f32 -> bf16c (RNE) + exact msqg ----------------
__global__ __launch_bounds__(256) void convert_kernel(
    const float* __restrict__ mbl,
    unsigned short* __restrict__ bf16c,   // [NPAN*TNP][D]
    float* __restrict__ msqg,             // [NPAN*TNP]
    int N) {
  const int nb = blockIdx.x;
  const int tid = threadIdx.x;
  const int r = tid >> 1, h = tid & 1;
  const int gn = nb * TNP + r;
  const bool ok = gn < N;
  const float* src = mbl + (size_t)(ok ? gn : 0) * D + h * 32;
  unsigned short* dst = bf16c + (size_t)gn * D + h * 32;
  float s = 0.f;
#pragma unroll
  for (int kc = 0; kc < 6; ++kc) {
    uint4 w[4];
    if (ok) {
#pragma unroll
      for (int i = 0; i < 4; ++i) {
        float4 f0 = *(const float4*)(src + kc * BK + i * 8);
        float4 f1 = *(const float4*)(src + kc * BK + i * 8 + 4);
        s += f0.x*f0.x + f0.y*f0.y + f0.z*f0.z + f0.w*f0.w
           + f1.x*f1.x + f1.y*f1.y + f1.z*f1.z + f1.w*f1.w;
        w[i] = (uint4){ pack2(f0.x,f0.y), pack2(f0.z,f0.w), pack2(f1.x,f1.y), pack2(f1.z,f1.w) };
      }
    } else {
#pragma unroll
      for (int i = 0; i < 4; ++i) w[i] = (uint4){0u,0u,0u,0u};
    }
#pragma unroll
    for (int i = 0; i < 4; ++i) *(uint4*)(dst + kc * BK + i * 8) = w[i];
  }
  s += __shfl_xor(s, 1);
  if (h == 0) msqg[gn] = ok ? s : 1e30f;
}

__device__ __forceinline__ void atomic_fmin(float* addr, float val) {
  unsigned* ua = (unsigned*)addr;
  float cur = __uint_as_float(atomicAdd(ua, 0u));
  while (val < cur) {
    unsigned assumed = __float_as_uint(cur);
    unsigned old = atomicCAS(ua, assumed, __float_as_uint(val));
    if (old == assumed) break;
    cur = __uint_as_float(old);
  }
}

// ---------------- score (main): bf16 staged from bf16c, no convert in loop ----------------
__global__ __launch_bounds__(256, 2) void score_kernel(
    const unsigned short* __restrict__ bf16c,
    const unsigned short* __restrict__ pbf,
    const float* __restrict__ msqg,
    float* __restrict__ tilemin,   // [q][NSUBP]
    int Q, int NSUBP, int QP, int q8, int r8) {
  __shared__ alignas(16) unsigned short lB0[TNP * LROW];
  __shared__ alignas(16) unsigned short lB1[TNP * LROW];

  const int tid = threadIdx.x;
  const int lane = tid & 63;
  const int wid = tid >> 6;          // wave = 64q sub-tile
  const int fr = lane & 15;
  const int g = lane >> 4;

  // bijective XCD swizzle (m204), qp-fast logical order
  const int flat = blockIdx.x;
  const int xcd = flat & 7, idx = flat >> 3;
  const int wg = (xcd < r8 ? xcd * (q8 + 1) : r8 * (q8 + 1) + (xcd - r8) * q8) + idx;
  const int nb = wg / QP;
  const int qp = wg - nb * QP;
  const int qbase = qp * PQ;
  const int nbase = nb * TNP;

  // B staging: thread t -> row t>>1, half t&1 (32 bf16 = 64B per chunk)
  const int brow = tid >> 1, h = tid & 1;
  const unsigned short* bptr = bf16c + (size_t)(nbase + brow) * D + h * 32;
  const int boff = brow * LROW + h * 32;

  // A: row = qbase + wid*64 + mf*16 + fr; elem = kc*64 + ks*32 + g*8
  const unsigned short* abase = pbf + (size_t)(qbase + wid * 64 + fr) * D + g * 8;

  f32x4 acc[4][8];
#pragma unroll
  for (int i = 0; i < 4; ++i)
#pragma unroll
    for (int j = 0; j < 8; ++j) acc[i][j] = (f32x4){0.f, 0.f, 0.f, 0.f};
  uint4 st[4];
  short8v a[8];

  auto bload = [&](int kc) {
#pragma unroll
    for (int i = 0; i < 4; ++i) st[i] = *(const uint4*)(bptr + kc * BK + i * 8);
  };
  auto bwr = [&](unsigned short* base) {
#pragma unroll
    for (int i = 0; i < 4; ++i) *(uint4*)(base + boff + i * 8) = st[i];
  };
  auto aload = [&](int kc) {
#pragma unroll
    for (int ks = 0; ks < 2; ++ks)
#pragma unroll
      for (int mf = 0; mf < 4; ++mf)
        a[ks * 4 + mf] = *(const short8v*)(abase + (size_t)mf * 16 * D + kc * BK + ks * 32);
  };
  auto compute = [&](const unsigned short* buf) {
#pragma unroll
    for (int ks = 0; ks < 2; ++ks) {
#pragma unroll
      for (int half = 0; half < 2; ++half) {
        short8v b4[4];
#pragma unroll
        for (int nf = 0; nf < 4; ++nf)
          b4[nf] = *(const short8v*)(&buf[((half * 4 + nf) * 16 + fr) * LROW + (ks * 4 + g) * 8]);
#pragma unroll
        for (int mf = 0; mf < 4; ++mf)
#pragma unroll
          for (int nf = 0; nf < 4; ++nf)
            acc[mf][half * 4 + nf] = __builtin_amdgcn_mfma_f32_16x16x32_bf16(
                a[ks * 4 + mf], b4[nf], acc[mf][half * 4 + nf], 0, 0, 0);
      }
    }
  };

  // prologue
  bload(0); bwr(lB0);
  __syncthreads();
  // phase k: aload(k) [oldest -> counted wait]; bload(k+1) [stays in flight under compute];
  //          compute(k); vmcnt(0)+bwr(k+1); barrier
  aload(0); bload(1); compute(lB0); bwr(lB1); __syncthreads();
  aload(1); bload(2); compute(lB1); bwr(lB0); __syncthreads();
  aload(2); bload(3); compute(lB0); bwr(lB1); __syncthreads();
  aload(3); bload(4); compute(lB1); bwr(lB0); __syncthreads();
  aload(4); bload(5); compute(lB0); bwr(lB1); __syncthreads();
  aload(5);           compute(lB1);

  // epilogue: msq from precomputed global (L2-hot), per-(q, 32-row subchunk) min
  float mq[8];
#pragma unroll
  for (int nf = 0; nf < 8; ++nf) mq[nf] = msqg[nbase + nf * 16 + fr];

#pragma unroll
  for (int mf = 0; mf < 4; ++mf) {
#pragma unroll
    for (int j = 0; j < 4; ++j) {
      float v[4];
#pragma unroll
      for (int s = 0; s < 4; ++s)
        v[s] = fminf(mq[2 * s] - 2.f * acc[mf][2 * s][j],
                     mq[2 * s + 1] - 2.f * acc[mf][2 * s + 1][j]);
#pragma unroll
      for (int d2 = 1; d2 < 16; d2 <<= 1)
#pragma unroll
        for (int s = 0; s < 4; ++s) v[s] = fminf(v[s], __shfl_xor(v[s], d2));
      if (fr == 0) {
        const int q = qbase + wid * 64 + mf * 16 + g * 4 + j;
        *(float4*)&tilemin[(size_t)q * NSUBP + nb * 4] = (float4){v[0], v[1], v[2], v[3]};
      }
    }
  }
}

// ---------------- fallback score (round-10 style, inline convert, atomic per-q) ----------------
__global__ __launch_bounds__(256, 2) void score_fb_kernel(
    const float* __restrict__ mbl,
    const unsigned short* __restrict__ pbf,
    float* __restrict__ d2min,
    int Q, int N, int QP, int q8, int r8) {
  __shared__ alignas(16) unsigned short lB0[TNP * LROW];
  __shared__ alignas(16) unsigned short lB1[TNP * LROW];
  __shared__ float msqH[TNP * 2];
  __shared__ float msqF[TNP];

  const int tid = threadIdx.x;
  const int lane = tid & 63;
  const int wid = tid >> 6;
  const int fr = lane & 15;
  const int g = lane >> 4;
  const int flat = blockIdx.x;
  const int xcd = flat & 7, idx = flat >> 3;
  const int wg = (xcd < r8 ? xcd * (q8 + 1) : r8 * (q8 + 1) + (xcd - r8) * q8) + idx;
  const int nb = wg / QP;
  const int qp = wg - nb * QP;
  const int qbase = qp * PQ;
  const int nbase = nb * TNP;
  const int brow = tid >> 1, h = tid & 1;
  const int gn = nbase + brow;
  const float* bptr = mbl + (size_t)((gn < N) ? gn : 0) * D + h * 32;
  const int boff = brow * LROW + h * 32;
  const unsigned short* abase = pbf + (size_t)(qbase + wid * 64 + fr) * D + g * 8;

  f32x4 acc[4][8];
#pragma unroll
  for (int i = 0; i < 4; ++i)
#pragma unroll
    for (int j = 0; j < 8; ++j) acc[i][j] = (f32x4){0.f, 0.f, 0.f, 0.f};
  float msqreg = 0.f;
  float4 breg[8];
  short8v a[8];

  auto bload = [&](int kc) {
    const float* src = bptr + kc * BK;
#pragma unroll
    for (int i = 0; i < 8; ++i) breg[i] = *(const float4*)(src + i * 4);
  };
  auto bwrite = [&](unsigned short* base) {
    float s = 0.f;
    uint4 w[4];
#pragma unroll
    for (int i = 0; i < 4; ++i) {
      float4 f0 = breg[2 * i], f1 = breg[2 * i + 1];
      s += f0.x*f0.x + f0.y*f0.y + f0.z*f0.z + f0.w*f0.w
         + f1.x*f1.x + f1.y*f1.y + f1.z*f1.z + f1.w*f1.w;
      w[i] = (uint4){ pack2(f0.x,f0.y), pack2(f0.z,f0.w), pack2(f1.x,f1.y), pack2(f1.z,f1.w) };
    }
#pragma unroll
    for (int i = 0; i < 4; ++i) *(uint4*)(base + boff + i * 8) = w[i];
    msqreg += s;
  };
  auto aload = [&](int kc) {
#pragma unroll
    for (int ks = 0; ks < 2; ++ks)
#pragma unroll
      for (int mf = 0; mf < 4; ++mf)
        a[ks * 4 + mf] = *(const short8v*)(abase + (size_t)mf * 16 * D + kc * BK + ks * 32);
  };
  auto compute = [&](const unsigned short* buf) {
#pragma unroll
    for (int ks = 0; ks < 2; ++ks)
#pragma unroll
      for (int half = 0; half < 2; ++half) {
        short8v b4[4];
#pragma unroll
        for (int nf = 0; nf < 4; ++nf)
          b4[nf] = *(const short8v*)(&buf[((half * 4 + nf) * 16 + fr) * LROW + (ks * 4 + g) * 8]);
#pragma unroll
        for (int mf = 0; mf < 4; ++mf)
#pragma unroll
          for (int nf = 0; nf < 4; ++nf)
            acc[mf][half * 4 + nf] = __builtin_amdgcn_mfma_f32_16x16x32_bf16(
                a[ks * 4 + mf], b4[nf], acc[mf][half * 4 + nf], 0, 0, 0);
      }
  };

  bload(0); bwrite(lB0); __syncthreads();
  aload(0); bload(1); compute(lB0); bwrite(lB1); __syncthreads();
  aload(1); bload(2); compute(lB1); bwrite(lB0); __syncthreads();
  aload(2); bload(3); compute(lB0); bwrite(lB1); __syncthreads();
  aload(3); bload(4); compute(lB1); bwrite(lB0); __syncthreads();
  aload(4); bload(5); compute(lB0); bwrite(lB1); __syncthreads();
  aload(5);           compute(lB1);              __syncthreads();

  msqH[tid] = msqreg;
  __syncthreads();
  if (tid < TNP) msqF[tid] = (nbase + tid < N) ? (msqH[2 * tid] + msqH[2 * tid + 1]) : 1e30f;
  __syncthreads();

  float mq[8];
#pragma unroll
  for (int nf = 0; nf < 8; ++nf) mq[nf] = msqF[nf * 16 + fr];

#pragma unroll
  for (int mf = 0; mf < 4; ++mf) {
#pragma unroll
    for (int j = 0; j < 4; ++j) {
      float v[4];
#pragma unroll
      for (int s = 0; s < 4; ++s)
        v[s] = fminf(mq[2 * s] - 2.f * acc[mf][2 * s][j],
                     mq[2 * s + 1] - 2.f * acc[mf][2 * s + 1][j]);
#pragma unroll
      for (int d2 = 1; d2 < 16; d2 <<= 1)
#pragma unroll
        for (int s = 0; s < 4; ++s) v[s] = fminf(v[s], __shfl_xor(v[s], d2));
      if (fr == 0) {
        const int q = qbase + wid * 64 + mf * 16 + g * 4 + j;
        atomic_fmin(&d2min[q], fminf(fminf(v[0], v[1]), fminf(v[2], v[3])));
      }
    }
  }
}

// ---------------- helpers ----------------
__global__ void init_inf_kernel(float* __restrict__ p, int n) {
  int i = blockIdx.x * 256 + threadIdx.x;
  if (i < n) p[i] = 1e30f;
}
__global__ void final_dmin_kernel(const float* __restrict__ d2min,
                                  const float* __restrict__ psq,
                                  float* __restrict__ dmin, int Q) {
  int q = blockIdx.x * 256 + threadIdx.x;
  if (q < Q) dmin[q] = sqrtf(fmaxf(psq[q] + d2min[q], 0.f));
}

__device__ __forceinline__ float block_min(float v, float* red) {
#pragma unroll
  for (int d = 1; d < 64; d <<= 1) v = fminf(v, __shfl_xor(v, d));
  if ((threadIdx.x & 63) == 0) red[threadIdx.x >> 6] = v;
  __syncthreads();
  const float r = fminf(fminf(red[0], red[1]), fminf(red[2], red[3]));
  __syncthreads();
  return r;
}
__device__ __forceinline__ float block_max(float v, float* red) {
#pragma unroll
  for (int d = 1; d < 64; d <<= 1) v = fmaxf(v, __shfl_xor(v, d));
  if ((threadIdx.x & 63) == 0) red[threadIdx.x >> 6] = v;
  __syncthreads();
  const float r = fmaxf(fmaxf(red[0], red[1]), fmaxf(red[2], red[3]));
  __syncthreads();
  return r;
}

// ---------------- refine: grid (Q, 4); per-segment candidates -> atomic d2min ----------------
// Correctness of per-segment threshold: each segment's min subchunk always passes its own
// threshold, so the global-best subchunk is exactly evaluated in its segment.
__global__ __launch_bounds__(256) void refine_kernel(
    const float* __restrict__ mbl,
    const float* __restrict__ pf32,
    const float* __restrict__ tm,    // [Q][NSUBP]
    float* __restrict__ d2min,
    int Q, int N, int NSUB, int NSUBP) {
  __shared__ int cnt;
  __shared__ int cand[64];
  __shared__ float red[4];
  const int q = blockIdx.x;
  const int seg = blockIdx.y;
  const int tid = threadIdx.x;
  if (tid == 0) cnt = 0;
  __syncthreads();

  const int SEG = (NSUB + 3) >> 2;
  const int r0 = seg * SEG;
  const int r1 = min(NSUB, r0 + SEG);
  const float* rowp = tm + (size_t)q * NSUBP;
  float m = 1e30f;
  for (int r = r0 + tid; r < r1; r += 256) m = fminf(m, rowp[r]);
  const float gm = block_min(m, red);
  const float thr = gm + 0.25f;   // 2x margin over worst-case bf16 dot error

  for (int r = r0 + tid; r < r1; r += 256)
    if (rowp[r] <= thr) { int i = atomicAdd(&cnt, 1); if (i < 64) cand[i] = r; }
  __syncthreads();
  const int nc = min(cnt, 64);

  const int row8 = tid >> 3, oct = tid & 7;
  const float* prow = pf32 + (size_t)q * D + oct * 48;
  float4 pr[12];
#pragma unroll
  for (int i = 0; i < 12; ++i) pr[i] = *(const float4*)(prow + i * 4);

  float best = 1e30f;
  for (int c = 0; c < nc; ++c) {
    const int n = cand[c] * 32 + row8;
    float v;
    if (n < N) {
      const float* mr = mbl + (size_t)n * D + oct * 48;
      float dot = 0.f, ms = 0.f;
#pragma unroll
      for (int i = 0; i < 12; ++i) {
        float4 aa = *(const float4*)(mr + i * 4);
        dot += aa.x*pr[i].x + aa.y*pr[i].y + aa.z*pr[i].z + aa.w*pr[i].w;
        ms  += aa.x*aa.x + aa.y*aa.y + aa.z*aa.z + aa.w*aa.w;
      }
      v = ms - 2.f * dot;
    } else {
      v = 1e30f;
    }
#pragma unroll
    for (int d2 = 1; d2 < 8; d2 <<= 1) {
      float o = __shfl_xor(v, d2);
      v = (n < N) ? v + o : 1e30f;
    }
    best = fminf(best, v);
  }
  best = block_min(best, red);
  if (tid == 0) atomic_fmin(&d2min[q], best);
}

// ---------------- global branch ----------------
__global__ __launch_bounds__(256) void gmin_kernel(
    const float* __restrict__ mbg,
    const float* __restrict__ gf32,
    const float* __restrict__ gsq,
    float* __restrict__ gpartG,
    int M) {
  __shared__ float red[4];
  const int b = blockIdx.x, s = blockIdx.y;
  const int tid = threadIdx.x;
  const int sl = (M + 31) / 32;
  const int row = s * sl + tid;
  const float* g = gf32 + (size_t)b * D;
  float v = 1e30f;
  if (tid < sl && row < M) {
    const float* mr = mbg + (size_t)row * D;
    float dot = 0.f, ms = 0.f;
#pragma unroll 4
    for (int k = 0; k < D; k += 4) {
      float4 aa = *(const float4*)(mr + k);
      float4 p = *(const float4*)(g + k);
      dot += aa.x*p.x + aa.y*p.y + aa.z*p.z + aa.w*p.w;
      ms  += aa.x*aa.x + aa.y*aa.y + aa.z*aa.z + aa.w*aa.w;
    }
    v = gsq[b] + ms - 2.f * dot;
  }
  v = block_min(v, red);
  if (tid == 0) gpartG[b * 32 + s] = v;
}

// ---------------- combine ----------------
__global__ __launch_bounds__(256) void out_kernel(
    const float* __restrict__ gpartG,
    const float* __restrict__ dmin,
    float* __restrict__ out,
    int P) {
  __shared__ float red[4];
  const int b = blockIdx.x;
  const int tid = threadIdx.x;
  float v = (tid < P) ? dmin[(size_t)b * P + tid] : -1e30f;
  const float local = block_max(v, red);
  float gm = (tid < 32) ? gpartG[b * 32 + tid] : 1e30f;
  gm = block_min(gm, red);
  if (tid == 0) out[b] = 0.7f * local + 0.3f * sqrtf(fmaxf(gm, 0.f));
}

extern "C" void kernel_launch(void* const* d_in, const int* in_sizes, int n_in,
                              void* d_out, int out_size, void* d_ws, size_t ws_size,
                              hipStream_t stream) {
  const float* patches   = (const float*)d_in[0];
  const float* globals_x = (const float*)d_in[1];
  const float* mbl       = (const float*)d_in[2];
  const float* mbg       = (const float*)d_in[3];
  float* out = (float*)d_out;

  const int Q = in_sizes[0] / D;          // 1024
  const int B = in_sizes[1] / D;          // 4
  const int N = in_sizes[2] / D;          // 100000
  const int M = in_sizes[3] / D;          // 2000
  const int P = Q / B;                    // 256
  const int NPAN = (N + TNP - 1) / TNP;   // 782
  const int NPAD = NPAN * TNP;            // 100096
  const int NSUB = NPAN * 4;              // 3128
  const int NSUBP = ((NSUB + 63) / 64) * 64;  // 3136
  const int QP = (Q + PQ - 1) / PQ;       // 4
  const int nwg = QP * NPAN;              // 3128
  const int q8 = nwg / 8, r8 = nwg % 8;

  char* w = (char*)d_ws;
  char* wend = (char*)d_ws + ws_size;
  auto alloc = [&](size_t bytes) {
    char* p = w;
    w += (bytes + 255) & ~(size_t)255;
    return p;
  };
  float*          pf32   = (float*)alloc((size_t)Q * D * sizeof(float));
  unsigned short* pbf    = (unsigned short*)alloc((size_t)Q * D * sizeof(unsigned short));
  float*          psq    = (float*)alloc((size_t)Q * sizeof(float));
  float*          gf32   = (float*)alloc((size_t)B * D * sizeof(float));
  float*          gsqp   = (float*)alloc((size_t)B * sizeof(float));
  float*          dmin   = (float*)alloc((size_t)Q * sizeof(float));
  float*          gpartG = (float*)alloc((size_t)B * 32 * sizeof(float));
  float*          d2min  = (float*)alloc((size_t)Q * sizeof(float));
  if (w > wend) return;

  const size_t bf16c_b = (size_t)NPAD * D * sizeof(unsigned short);
  const size_t msqg_b  = (size_t)NPAD * sizeof(float);
  const size_t tm_b    = (size_t)Q * NSUBP * sizeof(float);
  const size_t need = ((bf16c_b + 255) & ~(size_t)255) + ((msqg_b + 255) & ~(size_t)255) +
                      ((tm_b + 255) & ~(size_t)255);
  const int full = ((size_t)(wend - w) >= need) ? 1 : 0;

  init_inf_kernel<<<(Q + 255) / 256, 256, 0, stream>>>(d2min, Q);
  prep_kernel<<<Q + B, 64, 0, stream>>>(patches, globals_x, pf32, pbf, psq, gf32, gsqp, Q);

  if (full) {
    unsigned short* bf16c = (unsigned short*)alloc(bf16c_b);
    float*          msqg  = (float*)alloc(msqg_b);
    float*          tm    = (float*)alloc(tm_b);
    convert_kernel<<<NPAN, 256, 0, stream>>>(mbl, bf16c, msqg, N);
    score_kernel<<<nwg, 256, 0, stream>>>(bf16c, pbf, msqg, tm, Q, NSUBP, QP, q8, r8);
    refine_kernel<<<dim3(Q, 4), 256, 0, stream>>>(mbl, pf32, tm, d2min, Q, N, NSUB, NSUBP);
  } else {
    score_fb_kernel<<<nwg, 256, 0, stream>>>(mbl, pbf, d2min, Q, N, QP, q8, r8);
  }
  final_dmin_kernel<<<(Q + 255) / 256, 256, 0, stream>>>(d2min, psq, dmin, Q);
  gmin_kernel<<<dim3(B, 32), 256, 0, stream>>>(mbg, gf32, gsqp, gpartG, M);
  out_kernel<<<B, 256, 0, stream>>>(gpartG, dmin, out, P);
}